// Round 14
// baseline (138.032 us; speedup 1.0000x reference)
//
#include <hip/hip_runtime.h>
#include <hip/hip_bf16.h>
#include <stdint.h>

typedef __bf16 bf16x8 __attribute__((ext_vector_type(8)));
typedef float f32x4 __attribute__((ext_vector_type(4)));
typedef unsigned short us4v __attribute__((ext_vector_type(4)));
typedef unsigned short us8v __attribute__((ext_vector_type(8)));

#define B_   2
#define T_   2048
#define C_   1024
#define NH_  16
#define HD_  64

__device__ __forceinline__ unsigned short f2bf(float f) {
  unsigned int u = __builtin_bit_cast(unsigned int, f);
  u += 0x7fffu + ((u >> 16) & 1u);           // RNE
  return (unsigned short)(u >> 16);
}
__device__ __forceinline__ float bf2f(unsigned short u) {
  unsigned int x = ((unsigned int)u) << 16;
  return __builtin_bit_cast(float, x);
}

__device__ __forceinline__ void gload16(const void* g, void* l) {
  __builtin_amdgcn_global_load_lds(
      (const __attribute__((address_space(1))) unsigned int*)g,
      (__attribute__((address_space(3))) unsigned int*)l, 16, 0, 0);
}

__device__ __forceinline__ f32x4 mfma16(bf16x8 a, bf16x8 b, f32x4 c) {
  return __builtin_amdgcn_mfma_f32_16x16x32_bf16(a, b, c, 0, 0, 0);
}

// ---------------- cast / transpose ----------------
__global__ __launch_bounds__(256) void cast_x_kernel(const float4* __restrict__ in,
                                                     us4v* __restrict__ out) {
  int i = blockIdx.x * 256 + threadIdx.x;
  float4 f = in[i];
  us4v o; o[0] = f2bf(f.x); o[1] = f2bf(f.y); o[2] = f2bf(f.z); o[3] = f2bf(f.w);
  out[i] = o;
}

// w: (K x N) fp32 row-major  ->  wT: (N x K) bf16 row-major
__global__ __launch_bounds__(256) void transpose_cast_kernel(const float* __restrict__ w,
                                                             unsigned short* __restrict__ wT,
                                                             int K, int N) {
  __shared__ float tile[32][33];
  int n0 = blockIdx.x * 32, k0 = blockIdx.y * 32;
  int tx = threadIdx.x, ty = threadIdx.y;   // 32 x 8
  #pragma unroll
  for (int i = 0; i < 4; ++i)
    tile[ty + 8*i][tx] = w[(size_t)(k0 + ty + 8*i) * N + n0 + tx];
  __syncthreads();
  #pragma unroll
  for (int i = 0; i < 4; ++i)
    wT[(size_t)(n0 + ty + 8*i) * K + k0 + tx] = f2bf(tile[tx][ty + 8*i]);
}

// ---------------- GEMM core v2: BK=32, 3-buffer rotation, 1 barrier, counted vmcnt ----------------
// C[m,n] = sum_k A[m,k]*Bt[n,k]. Tile 128x128, 256 thr (4 waves, 64x64/wave).
// LDS per operand: 3 bufs x (128 rows x 32 cols) us. Granule(8us) swizzle:
// phys = logical ^ ((row>>1)&3) on both staged source and fragment read
// (8 lanes/bank-quad = balanced b128 pattern).
// Pipeline: stage(k+2) issued AFTER barrier(k); buf (k+2)%3 == (k-1)%3 is free
// because barrier(k) implies all threads finished compute(k-1).
__device__ __forceinline__ void gemm_core2(const unsigned short* __restrict__ A,
                                           const unsigned short* __restrict__ Bt,
                                           int K, int m0, int n0,
                                           unsigned short* lA, unsigned short* lB,
                                           f32x4 acc[4][4]) {
  const int t = threadIdx.x;
  const int lane = t & 63, w = t >> 6;
  const int wm = w >> 1, wn = w & 1;
  const int g = lane >> 4, r16 = lane & 15;
  #pragma unroll
  for (int i = 0; i < 4; ++i)
    #pragma unroll
    for (int j = 0; j < 4; ++j) acc[i][j] = (f32x4){0.f, 0.f, 0.f, 0.f};

  const int NK = K >> 5;                       // BK = 32
  // staging: slots t and t+256; row = slot>>2, phys granule = slot&3,
  // source logical granule q = (slot&3) ^ ((row>>1)&3)
  const int r0 = t >> 2;
  const int q0 = (t & 3) ^ ((r0 >> 1) & 3);
  const int r1 = r0 + 64;
  const int q1 = (t & 3) ^ ((r1 >> 1) & 3);    // == q0 (bits 1-2 of row unchanged)
  const int fsw = (r16 >> 1) & 3;              // fragment-read swizzle

#define G2_STAGE(ks)                                                              \
  {                                                                               \
    unsigned short* dA = lA + ((ks) % 3) * 4096;                                  \
    unsigned short* dB = lB + ((ks) % 3) * 4096;                                  \
    gload16(A  + (size_t)(m0 + r0) * K + (ks) * 32 + q0 * 8, dA + t * 8);         \
    gload16(A  + (size_t)(m0 + r1) * K + (ks) * 32 + q1 * 8, dA + (t + 256) * 8); \
    gload16(Bt + (size_t)(n0 + r0) * K + (ks) * 32 + q0 * 8, dB + t * 8);         \
    gload16(Bt + (size_t)(n0 + r1) * K + (ks) * 32 + q1 * 8, dB + (t + 256) * 8); \
  }

  G2_STAGE(0);
  G2_STAGE(1);

  for (int ks = 0; ks < NK; ++ks) {
    if (ks + 1 < NK) { asm volatile("s_waitcnt vmcnt(4)" ::: "memory"); }
    else             { asm volatile("s_waitcnt vmcnt(0)" ::: "memory"); }
    __syncthreads();
    if (ks + 2 < NK) G2_STAGE(ks + 2);

    const unsigned short* bufA = lA + (ks % 3) * 4096;
    const unsigned short* bufB = lB + (ks % 3) * 4096;
    bf16x8 af[4], bfr[4];
    #pragma unroll
    for (int mi = 0; mi < 4; ++mi)
      af[mi] = *(const bf16x8*)(bufA + (wm * 64 + mi * 16 + r16) * 32 + (g ^ fsw) * 8);
    #pragma unroll
    for (int ni = 0; ni < 4; ++ni)
      bfr[ni] = *(const bf16x8*)(bufB + (wn * 64 + ni * 16 + r16) * 32 + (g ^ fsw) * 8);
    #pragma unroll
    for (int mi = 0; mi < 4; ++mi)
      #pragma unroll
      for (int ni = 0; ni < 4; ++ni)
        acc[mi][ni] = mfma16(af[mi], bfr[ni], acc[mi][ni]);
  }
#undef G2_STAGE
}

// XCD-aware bijective swizzle of the linear workgroup id (nwg % 8 == 0)
__device__ __forceinline__ int xcd_swz(int flat, int nwg) {
  int cpx = nwg >> 3;
  return (flat & 7) * cpx + (flat >> 3);
}

__global__ __launch_bounds__(256) void gemm_qkv_kernel(const unsigned short* __restrict__ xb,
                                                       const unsigned short* __restrict__ wT,
                                                       unsigned short* __restrict__ qb,
                                                       unsigned short* __restrict__ kb,
                                                       unsigned short* __restrict__ vb) {
  __shared__ unsigned short lA[3 * 128 * 32];
  __shared__ unsigned short lB[3 * 128 * 32];
  f32x4 acc[4][4];
  const int nbx = 3 * C_ / 128;
  int flat = xcd_swz(blockIdx.y * nbx + blockIdx.x, nbx * ((B_ * T_) / 128));
  const int m0 = (flat / nbx) * 128, n0 = (flat % nbx) * 128;
  gemm_core2(xb, wT, C_, m0, n0, lA, lB, acc);
  const int t = threadIdx.x, lane = t & 63, w = t >> 6;
  const int wm = w >> 1, wn = w & 1, g = lane >> 4, r16 = lane & 15;
  #pragma unroll
  for (int mi = 0; mi < 4; ++mi)
    #pragma unroll
    for (int ni = 0; ni < 4; ++ni)
      #pragma unroll
      for (int j = 0; j < 4; ++j) {
        int gm = m0 + wm * 64 + mi * 16 + g * 4 + j;
        int gn = n0 + wn * 64 + ni * 16 + r16;
        int b = gm >> 11, tt = gm & 2047;
        int s = gn >> 10, rem = gn & 1023;
        int h = rem >> 6, d = rem & 63;
        unsigned short val = f2bf(acc[mi][ni][j]);
        size_t idx = ((size_t)(b * NH_ + h) * T_ + tt) * HD_ + d;
        if (s == 0)      qb[idx] = val;
        else if (s == 1) kb[idx] = val;
        else             vb[idx] = val;
      }
}

__global__ __launch_bounds__(256) void gemm_proj_kernel(const unsigned short* __restrict__ ab,
                                                        const unsigned short* __restrict__ wT,
                                                        float* __restrict__ out) {
  __shared__ unsigned short lA[3 * 128 * 32];
  __shared__ unsigned short lB[3 * 128 * 32];
  f32x4 acc[4][4];
  const int nbx = C_ / 128;
  int flat = xcd_swz(blockIdx.y * nbx + blockIdx.x, nbx * ((B_ * T_) / 128));
  const int m0 = (flat / nbx) * 128, n0 = (flat % nbx) * 128;
  gemm_core2(ab, wT, C_, m0, n0, lA, lB, acc);
  const int t = threadIdx.x, lane = t & 63, w = t >> 6;
  const int wm = w >> 1, wn = w & 1, g = lane >> 4, r16 = lane & 15;
  #pragma unroll
  for (int mi = 0; mi < 4; ++mi)
    #pragma unroll
    for (int ni = 0; ni < 4; ++ni)
      #pragma unroll
      for (int j = 0; j < 4; ++j) {
        int gm = m0 + wm * 64 + mi * 16 + g * 4 + j;
        int gn = n0 + wn * 64 + ni * 16 + r16;
        out[(size_t)gm * C_ + gn] = acc[mi][ni][j];
      }
}

// ---------------- Flash attention v13 (unchanged, verified round 13) ----------------
__global__ __launch_bounds__(256, 4) void attn_kernel(const unsigned short* __restrict__ qb,
                                                      const unsigned short* __restrict__ kb,
                                                      const unsigned short* __restrict__ vb,
                                                      unsigned short* __restrict__ ao,
                                                      unsigned short* __restrict__ partB,
                                                      float* __restrict__ mlbuf) {
  __shared__ unsigned short LDS[20480];
  const int L = blockIdx.x;
  const int inner = L >> 3;
  const int bh = (L & 7) * 4 + (inner / 48);
  const int bx = inner % 48;
  int tile, kvLo, kvHi, mode;   // mode: 0=full, 1=halfA, 2=halfB
  if (bx < 16)      { tile = 16 + bx; kvLo = 0;  kvHi = 16;       mode = 1; }
  else if (bx < 32) { tile = 47 - bx; kvLo = 16; kvHi = tile + 1; mode = 2; }
  else              { tile = 47 - bx; kvLo = 0;  kvHi = tile + 1; mode = 0; }
  const int qt0 = tile * 64;
  const int len = kvHi - kvLo;
  const int t = threadIdx.x, lane = t & 63, w4 = t >> 6;   // w4 in 0..3
  const int g = lane >> 4, r16 = lane & 15;

  const unsigned short* Q  = qb + (size_t)bh * (T_ * HD_);
  const unsigned short* Kp = kb + (size_t)bh * (T_ * HD_);
  const unsigned short* Vp = vb + (size_t)bh * (T_ * HD_);

  // Q fragments (B-operand: lane holds Q[q=r16][k-octet g]), pre-scaled 1/8
  bf16x8 qf[2];
  {
    int qrow = qt0 + w4 * 16 + r16;
    #pragma unroll
    for (int kk = 0; kk < 2; ++kk) {
      us8v raw = *(const us8v*)(Q + (size_t)qrow * HD_ + kk * 32 + g * 8);
      bf16x8 qv;
      #pragma unroll
      for (int j = 0; j < 8; ++j) qv[j] = (__bf16)(bf2f(raw[j]) * 0.125f);
      qf[kk] = qv;
    }
  }

  f32x4 o[4];
  #pragma unroll
  for (int c = 0; c < 4; ++c) o[c] = (f32x4){0.f, 0.f, 0.f, 0.f};
  float mrun = -__builtin_inff(), lrun = 0.f;

  // staging constants (verified formulas)
  const int kr0 = t >> 3,         kp0 = (t & 7) ^ (kr0 & 7);   // rows 0..31
  const int kr1 = (t + 256) >> 3, kp1 = (t & 7) ^ (kr1 & 7);   // rows 32..63
  const int colp = (lane & 32) | ((lane & 12) << 1) | ((lane >> 2) & 4) | (lane & 3);
  const int cslot = colp >> 3, cwithin = colp & 7;

  // prologue: batches 0 and 1 (K DMA then V regs; 4 VMEM ops per batch)
  gload16(Kp + (size_t)(kvLo * 64 + kr0) * HD_ + kp0 * 8, LDS + t * 8);
  gload16(Kp + (size_t)(kvLo * 64 + kr1) * HD_ + kp1 * 8, LDS + (t + 256) * 8);
  us8v nvA0 = *(const us8v*)(Vp + (size_t)(kvLo * 64 + lane) * HD_ + w4 * 16);
  us8v nvA1 = *(const us8v*)(Vp + (size_t)(kvLo * 64 + lane) * HD_ + w4 * 16 + 8);
  us8v nvB0, nvB1;
  if (len > 1) {
    const int k1 = (kvLo + 1) * 64;
    gload16(Kp + (size_t)(k1 + kr0) * HD_ + kp0 * 8, LDS + 4096 + t * 8);
    gload16(Kp + (size_t)(k1 + kr1) * HD_ + kp1 * 8, LDS + 4096 + (t + 256) * 8);
    nvB0 = *(const us8v*)(Vp + (size_t)(k1 + lane) * HD_ + w4 * 16);
    nvB1 = *(const us8v*)(Vp + (size_t)(k1 + lane) * HD_ + w4 * 16 + 8);
  }

  for (int ii = 0; ii < len; ++ii) {
    const int it = kvLo + ii;
    const unsigned short* Kl = LDS + (ii % 3) * 4096;
    unsigned short* Vt = LDS + 12288 + (ii & 1) * 4096;

    if (ii + 1 < len) { asm volatile("s_waitcnt vmcnt(4)" ::: "memory"); }
    else              { asm volatile("s_waitcnt vmcnt(0)" ::: "memory"); }
    {
      us8v v0, v1;
      if (ii & 1) { v0 = nvB0; v1 = nvB1; } else { v0 = nvA0; v1 = nvA1; }
      #pragma unroll
      for (int u = 0; u < 8; ++u) {
        int d = w4 * 16 + u;                             // d&7 == u
        Vt[d * 64 + ((cslot ^ u) << 3) + cwithin] = v0[u];
      }
      #pragma unroll
      for (int u = 0; u < 8; ++u) {
        int d = w4 * 16 + 8 + u;
        Vt[d * 64 + ((cslot ^ u) << 3) + cwithin] = v1[u];
      }
    }
    __syncthreads();

    if (ii + 2 < len) {    // issue batch ii+2 (buf (ii+2)%3, nv set ii&1 — just freed)
      const int kn = (it + 2) * 64;
      unsigned short* Kn = LDS + ((ii + 2) % 3) * 4096;
      gload16(Kp + (size_t)(kn + kr0) * HD_ + kp0 * 8, Kn + t * 8);
      gload16(Kp + (size_t)(kn + kr1) * HD_ + kp1 * 8, Kn + (t + 256) * 8);
      if (ii & 1) {
        nvB0 = *(const us8v*)(Vp + (size_t)(kn + lane) * HD_ + w4 * 16);
        nvB1 = *(const us8v*)(Vp + (size_t)(kn + lane) * HD_ + w4 * 16 + 8);
      } else {
        nvA0 = *(const us8v*)(Vp + (size_t)(kn + lane) * HD_ + w4 * 16);
        nvA1 = *(const us8v*)(Vp + (size_t)(kn + lane) * HD_ + w4 * 16 + 8);
      }
    }

    {
      // S^T = K @ Q^T : s4t[c][j] = S[q=r16-row][kv = it*64 + 16c + 4g + j]
      f32x4 s4t[4];
      #pragma unroll
      for (int c = 0; c < 4; ++c) s4t[c] = (f32x4){0.f, 0.f, 0.f, 0.f};
      __builtin_amdgcn_s_setprio(1);
      #pragma unroll
      for (int c = 0; c < 4; ++c)
        #pragma unroll
        for (int kk = 0; kk < 2; ++kk) {
          int r = c * 16 + r16;
          int ps = (kk * 4 + g) ^ (r & 7);
          bf16x8 kf = *(const bf16x8*)(Kl + r * 64 + ps * 8);
          s4t[c] = mfma16(kf, qf[kk], s4t[c]);
        }
      __builtin_amdgcn_s_setprio(0);
      if (it == tile) {   // diagonal tile: mask kv_local > q_local
        int qloc = w4 * 16 + r16;
        #pragma unroll
        for (int c = 0; c < 4; ++c)
          #pragma unroll
          for (int j = 0; j < 4; ++j)
            if (c * 16 + g * 4 + j > qloc) s4t[c][j] = -1e30f;
      }
      // row max via max3-triples
      float t0 = fmaxf(fmaxf(s4t[0][0], s4t[0][1]), s4t[0][2]);
      float t1 = fmaxf(fmaxf(s4t[0][3], s4t[1][0]), s4t[1][1]);
      float t2 = fmaxf(fmaxf(s4t[1][2], s4t[1][3]), s4t[2][0]);
      float t3 = fmaxf(fmaxf(s4t[2][1], s4t[2][2]), s4t[2][3]);
      float t4 = fmaxf(fmaxf(s4t[3][0], s4t[3][1]), s4t[3][2]);
      float mx = fmaxf(fmaxf(fmaxf(t0, t1), fmaxf(t2, t3)),
                       fmaxf(t4, s4t[3][3]));
      mx = fmaxf(mx, __shfl_xor(mx, 16));
      mx = fmaxf(mx, __shfl_xor(mx, 32));
      // T13 defer-max: only rescale when max grew by > 8
      if (!__all(mx - mrun <= 8.0f)) {
        float mn = fmaxf(mrun, mx);
        float alpha = __expf(mrun - mn);
        mrun = mn;
        lrun *= alpha;
        #pragma unroll
        for (int c = 0; c < 4; ++c)
          #pragma unroll
          for (int j = 0; j < 4; ++j) o[c][j] *= alpha;
      }
      // P = exp(S - mrun); tree-sum
      float ps4[4];
      #pragma unroll
      for (int c = 0; c < 4; ++c) {
        #pragma unroll
        for (int j = 0; j < 4; ++j) s4t[c][j] = __expf(s4t[c][j] - mrun);
        ps4[c] = (s4t[c][0] + s4t[c][1]) + (s4t[c][2] + s4t[c][3]);
      }
      float rs = (ps4[0] + ps4[1]) + (ps4[2] + ps4[3]);
      rs += __shfl_xor(rs, 16);
      rs += __shfl_xor(rs, 32);
      lrun += rs;

      // P^T fragments in-register (B-operand): p[4h+e] = s4t[2kk+h][e]
      bf16x8 pf[2];
      #pragma unroll
      for (int kk = 0; kk < 2; ++kk) {
        bf16x8 p;
        #pragma unroll
        for (int j = 0; j < 4; ++j) {
          p[j]     = (__bf16)s4t[2 * kk][j];
          p[4 + j] = (__bf16)s4t[2 * kk + 1][j];
        }
        pf[kk] = p;
      }
      // O^T += V^T @ P^T : A-fragment = swizzled b128 from Vt
      __builtin_amdgcn_s_setprio(1);
      #pragma unroll
      for (int c = 0; c < 4; ++c) {
        int rv = c * 16 + r16;
        #pragma unroll
        for (int kk = 0; kk < 2; ++kk) {
          int slot = (4 * kk + g) ^ (r16 & 7);
          bf16x8 vf = *(const bf16x8*)(Vt + rv * 64 + slot * 8);
          o[c] = mfma16(vf, pf[kk], o[c]);
        }
      }
      __builtin_amdgcn_s_setprio(0);
    }
  }

  // write (m,l) for split halves (rows lane-owned by g==0 lanes)
  if (mode && g == 0) {
    int prow = (bh * 16 + (tile - 16)) * 64 + w4 * 16 + r16;
    float* mlp = mlbuf + (size_t)prow * 4;
    if (mode == 1) { mlp[0] = mrun; mlp[1] = lrun; }
    else           { mlp[2] = mrun; mlp[3] = lrun; }
  }

  // epilogue: normalized O -> unused K buffer (len%3) transpose -> coalesced store
  unsigned short* ep = LDS + (len % 3) * 4096 + w4 * 1024;
  float inv = 1.f / lrun;
  #pragma unroll
  for (int c = 0; c < 4; ++c) {
    us4v pk;
    #pragma unroll
    for (int j = 0; j < 4; ++j) pk[j] = f2bf(o[c][j] * inv);
    int slot = (4 * c + g) ^ r16;
    *(us4v*)(ep + r16 * 64 + slot * 4) = pk;
  }
  asm volatile("s_waitcnt lgkmcnt(0)" ::: "memory");
  __builtin_amdgcn_sched_barrier(0);
  {
    int q = lane >> 2, seg = lane & 3;
    us4v a0 = *(const us4v*)(ep + q * 64 + (((seg * 4 + 0) ^ q) & 15) * 4);
    us4v a1 = *(const us4v*)(ep + q * 64 + (((seg * 4 + 1) ^ q) & 15) * 4);
    us4v a2 = *(const us4v*)(ep + q * 64 + (((seg * 4 + 2) ^ q) & 15) * 4);
    us4v a3 = *(const us4v*)(ep + q * 64 + (((seg * 4 + 3) ^ q) & 15) * 4);
    us8v o0 = {a0[0],a0[1],a0[2],a0[3],a1[0],a1[1],a1[2],a1[3]};
    us8v o1 = {a2[0],a2[1],a2[2],a2[3],a3[0],a3[1],a3[2],a3[3]};
    if (mode != 2) {
      size_t rowg = (size_t)(bh >> 4) * T_ + qt0 + w4 * 16 + q;
      int colg = (bh & 15) * 64 + seg * 16;
      *(us8v*)(ao + rowg * C_ + colg)     = o0;
      *(us8v*)(ao + rowg * C_ + colg + 8) = o1;
    } else {
      size_t prow = (size_t)(bh * 16 + (tile - 16)) * 64 + w4 * 16 + q;
      *(us8v*)(partB + prow * 64 + seg * 16)     = o0;
      *(us8v*)(partB + prow * 64 + seg * 16 + 8) = o1;
    }
  }
}

// ---------------- merge kernel: combine halfA (in ao) with halfB ----------------
__global__ __launch_bounds__(256) void attn_merge_kernel(unsigned short* __restrict__ ao,
                                                         const unsigned short* __restrict__ partB,
                                                         const float* __restrict__ mlbuf) {
  const int blk = blockIdx.x;          // 512 = 32 bh x 16 ti
  const int bh = blk >> 4, ti = blk & 15;
  const int t = threadIdx.x;
  const int row = t >> 2, seg = t & 3;
  const size_t prow = (size_t)(bh * 16 + ti) * 64 + row;
  const float* mlp = mlbuf + prow * 4;
  float mA = mlp[0], lA = mlp[1], mB = mlp[2], lB = mlp[3];
  float m = fmaxf(mA, mB);
  float wA = lA * __expf(mA - m), wB = lB * __expf(mB - m);
  float rinv = 1.f / (wA + wB);
  wA *= rinv; wB *= rinv;
  size_t rowg = (size_t)(bh >> 4) * T_ + (16 + ti) * 64 + row;
  unsigned short* aop = ao + rowg * C_ + (bh & 15) * 64 + seg * 16;
  const unsigned short* obp = partB + prow * 64 + seg * 16;
  us8v oa0 = *(const us8v*)(aop);
  us8v oa1 = *(const us8v*)(aop + 8);
  us8v ob0 = *(const us8v*)(obp);
  us8v ob1 = *(const us8v*)(obp + 8);
  us8v r0, r1;
  #pragma unroll
  for (int j = 0; j < 8; ++j) {
    r0[j] = f2bf(bf2f(oa0[j]) * wA + bf2f(ob0[j]) * wB);
    r1[j] = f2bf(bf2f(oa1[j]) * wA + bf2f(ob1[j]) * wB);
  }
  *(us8v*)(aop)     = r0;
  *(us8v*)(aop + 8) = r1;
}

// ---------------- launch ----------------
extern "C" void kernel_launch(void* const* d_in, const int* in_sizes, int n_in,
                              void* d_out, int out_size, void* d_ws, size_t ws_size,
                              hipStream_t stream) {
  const float* x      = (const float*)d_in[0];
  const float* w_qkv  = (const float*)d_in[1];
  const float* w_proj = (const float*)d_in[2];
  float* out = (float*)d_out;
  char* ws = (char*)d_ws;

  unsigned short* xb     = (unsigned short*)(ws);              // 8 MB (reused as ao)
  unsigned short* wqkvT  = (unsigned short*)(ws + 8388608);    // 6 MB (reused: partB+ml)
  unsigned short* wprojT = (unsigned short*)(ws + 14680064);   // 2 MB
  unsigned short* qb     = (unsigned short*)(ws + 16777216);   // 8 MB
  unsigned short* kb     = (unsigned short*)(ws + 25165824);   // 8 MB
  unsigned short* vb     = (unsigned short*)(ws + 33554432);   // 8 MB
  unsigned short* ao     = xb;
  // partials live in the wqkvT region (dead after gemm_qkv):
  unsigned short* partB  = wqkvT;                              // 4 MB (32*16*64 rows x 64 d)
  float*          mlbuf  = (float*)(ws + 8388608 + 4194304);   // 512 KB (rows x 4 f32)

  cast_x_kernel<<<4096, 256, 0, stream>>>((const float4*)x, (us4v*)xb);
  transpose_cast_kernel<<<dim3(3 * C_ / 32, C_ / 32), dim3(32, 8), 0, stream>>>(
      w_qkv, wqkvT, C_, 3 * C_);
  transpose_cast_kernel<<<dim3(C_ / 32, C_ / 32), dim3(32, 8), 0, stream>>>(
      w_proj, wprojT, C_, C_);
  gemm_qkv_kernel<<<dim3(3 * C_ / 128, (B_ * T_) / 128), 256, 0, stream>>>(
      xb, wqkvT, qb, kb, vb);
  attn_kernel<<<dim3(1536), 256, 0, stream>>>(qb, kb, vb, ao, partB, mlbuf);
  attn_merge_kernel<<<512, 256, 0, stream>>>(ao, partB, mlbuf);
  gemm_proj_kernel<<<dim3(C_ / 128, (B_ * T_) / 128), 256, 0, stream>>>(
      ao, wprojT, out);
}

// Round 15
// 136.330 us; speedup vs baseline: 1.0125x; 1.0125x over previous
//
#include <hip/hip_runtime.h>
#include <hip/hip_bf16.h>
#include <stdint.h>

typedef __bf16 bf16x8 __attribute__((ext_vector_type(8)));
typedef float f32x4 __attribute__((ext_vector_type(4)));
typedef unsigned short us4v __attribute__((ext_vector_type(4)));
typedef unsigned short us8v __attribute__((ext_vector_type(8)));

#define B_   2
#define T_   2048
#define C_   1024
#define NH_  16
#define HD_  64

__device__ __forceinline__ unsigned short f2bf(float f) {
  unsigned int u = __builtin_bit_cast(unsigned int, f);
  u += 0x7fffu + ((u >> 16) & 1u);           // RNE
  return (unsigned short)(u >> 16);
}
__device__ __forceinline__ float bf2f(unsigned short u) {
  unsigned int x = ((unsigned int)u) << 16;
  return __builtin_bit_cast(float, x);
}

__device__ __forceinline__ void gload16(const void* g, void* l) {
  __builtin_amdgcn_global_load_lds(
      (const __attribute__((address_space(1))) unsigned int*)g,
      (__attribute__((address_space(3))) unsigned int*)l, 16, 0, 0);
}

__device__ __forceinline__ f32x4 mfma16(bf16x8 a, bf16x8 b, f32x4 c) {
  return __builtin_amdgcn_mfma_f32_16x16x32_bf16(a, b, c, 0, 0, 0);
}

// ---------------- cast / transpose ----------------
__global__ __launch_bounds__(256) void cast_x_kernel(const float4* __restrict__ in,
                                                     us4v* __restrict__ out) {
  int i = blockIdx.x * 256 + threadIdx.x;
  float4 f = in[i];
  us4v o; o[0] = f2bf(f.x); o[1] = f2bf(f.y); o[2] = f2bf(f.z); o[3] = f2bf(f.w);
  out[i] = o;
}

// w: (K x N) fp32 row-major  ->  wT: (N x K) bf16 row-major
__global__ __launch_bounds__(256) void transpose_cast_kernel(const float* __restrict__ w,
                                                             unsigned short* __restrict__ wT,
                                                             int K, int N) {
  __shared__ float tile[32][33];
  int n0 = blockIdx.x * 32, k0 = blockIdx.y * 32;
  int tx = threadIdx.x, ty = threadIdx.y;   // 32 x 8
  #pragma unroll
  for (int i = 0; i < 4; ++i)
    tile[ty + 8*i][tx] = w[(size_t)(k0 + ty + 8*i) * N + n0 + tx];
  __syncthreads();
  #pragma unroll
  for (int i = 0; i < 4; ++i)
    wT[(size_t)(n0 + ty + 8*i) * K + k0 + tx] = f2bf(tile[tx][ty + 8*i]);
}

// ---------------- GEMM core v3: BK=32, 2-buffer dbuf, 1 barrier, early stage ----------------
// C[m,n] = sum_k A[m,k]*Bt[n,k]. Tile 128x128, 256 thr (4 waves, 64x64/wave).
// LDS per operand: 2 bufs x (128 rows x 32 cols) us = 16 KB -> 32 KB total,
// 5 blocks/CU (round-0 occupancy restored; round-14's 3-buf 48 KB was the bug).
// Swizzle (proven numerically in round 14): granule phys = logical ^ ((row>>1)&3)
// on both the pre-swizzled global source and the fragment read.
// Order per step: vmcnt(0) -> barrier -> STAGE(ks+1) -> compute(ks).
//  - read safety: per-thread vmcnt(0) BEFORE barrier => after barrier all
//    threads' stage(ks) loads have landed (v11-verified ordering).
//  - buffer safety: barrier(ks) => compute(ks-1) done => buf (ks+1)&1 free.
//  - overlap: stage(ks+1) DMA flies during compute(ks)'s 16 MFMAs.
__device__ __forceinline__ void gemm_core2(const unsigned short* __restrict__ A,
                                           const unsigned short* __restrict__ Bt,
                                           int K, int m0, int n0,
                                           unsigned short* lA, unsigned short* lB,
                                           f32x4 acc[4][4]) {
  const int t = threadIdx.x;
  const int lane = t & 63, w = t >> 6;
  const int wm = w >> 1, wn = w & 1;
  const int g = lane >> 4, r16 = lane & 15;
  #pragma unroll
  for (int i = 0; i < 4; ++i)
    #pragma unroll
    for (int j = 0; j < 4; ++j) acc[i][j] = (f32x4){0.f, 0.f, 0.f, 0.f};

  const int NK = K >> 5;                       // BK = 32
  const int r0 = t >> 2;
  const int q0 = (t & 3) ^ ((r0 >> 1) & 3);
  const int r1 = r0 + 64;
  const int q1 = (t & 3) ^ ((r1 >> 1) & 3);    // == q0
  const int fsw = (r16 >> 1) & 3;              // fragment-read swizzle

#define G2_STAGE(ks)                                                              \
  {                                                                               \
    unsigned short* dA = lA + ((ks) & 1) * 4096;                                  \
    unsigned short* dB = lB + ((ks) & 1) * 4096;                                  \
    gload16(A  + (size_t)(m0 + r0) * K + (ks) * 32 + q0 * 8, dA + t * 8);         \
    gload16(A  + (size_t)(m0 + r1) * K + (ks) * 32 + q1 * 8, dA + (t + 256) * 8); \
    gload16(Bt + (size_t)(n0 + r0) * K + (ks) * 32 + q0 * 8, dB + t * 8);         \
    gload16(Bt + (size_t)(n0 + r1) * K + (ks) * 32 + q1 * 8, dB + (t + 256) * 8); \
  }

  G2_STAGE(0);

  for (int ks = 0; ks < NK; ++ks) {
    asm volatile("s_waitcnt vmcnt(0)" ::: "memory");   // own stage(ks) landed
    __syncthreads();                                   // => ALL stage(ks) landed
    if (ks + 1 < NK) G2_STAGE(ks + 1);                 // DMA overlaps compute(ks)

    const unsigned short* bufA = lA + (ks & 1) * 4096;
    const unsigned short* bufB = lB + (ks & 1) * 4096;
    bf16x8 af[4], bfr[4];
    #pragma unroll
    for (int mi = 0; mi < 4; ++mi)
      af[mi] = *(const bf16x8*)(bufA + (wm * 64 + mi * 16 + r16) * 32 + (g ^ fsw) * 8);
    #pragma unroll
    for (int ni = 0; ni < 4; ++ni)
      bfr[ni] = *(const bf16x8*)(bufB + (wn * 64 + ni * 16 + r16) * 32 + (g ^ fsw) * 8);
    #pragma unroll
    for (int mi = 0; mi < 4; ++mi)
      #pragma unroll
      for (int ni = 0; ni < 4; ++ni)
        acc[mi][ni] = mfma16(af[mi], bfr[ni], acc[mi][ni]);
  }
#undef G2_STAGE
}

// XCD-aware bijective swizzle of the linear workgroup id (nwg % 8 == 0)
__device__ __forceinline__ int xcd_swz(int flat, int nwg) {
  int cpx = nwg >> 3;
  return (flat & 7) * cpx + (flat >> 3);
}

__global__ __launch_bounds__(256) void gemm_qkv_kernel(const unsigned short* __restrict__ xb,
                                                       const unsigned short* __restrict__ wT,
                                                       unsigned short* __restrict__ qb,
                                                       unsigned short* __restrict__ kb,
                                                       unsigned short* __restrict__ vb) {
  __shared__ unsigned short lA[2 * 128 * 32];
  __shared__ unsigned short lB[2 * 128 * 32];
  f32x4 acc[4][4];
  const int nbx = 3 * C_ / 128;
  int flat = xcd_swz(blockIdx.y * nbx + blockIdx.x, nbx * ((B_ * T_) / 128));
  const int m0 = (flat / nbx) * 128, n0 = (flat % nbx) * 128;
  gemm_core2(xb, wT, C_, m0, n0, lA, lB, acc);
  const int t = threadIdx.x, lane = t & 63, w = t >> 6;
  const int wm = w >> 1, wn = w & 1, g = lane >> 4, r16 = lane & 15;
  #pragma unroll
  for (int mi = 0; mi < 4; ++mi)
    #pragma unroll
    for (int ni = 0; ni < 4; ++ni)
      #pragma unroll
      for (int j = 0; j < 4; ++j) {
        int gm = m0 + wm * 64 + mi * 16 + g * 4 + j;
        int gn = n0 + wn * 64 + ni * 16 + r16;
        int b = gm >> 11, tt = gm & 2047;
        int s = gn >> 10, rem = gn & 1023;
        int h = rem >> 6, d = rem & 63;
        unsigned short val = f2bf(acc[mi][ni][j]);
        size_t idx = ((size_t)(b * NH_ + h) * T_ + tt) * HD_ + d;
        if (s == 0)      qb[idx] = val;
        else if (s == 1) kb[idx] = val;
        else             vb[idx] = val;
      }
}

__global__ __launch_bounds__(256) void gemm_proj_kernel(const unsigned short* __restrict__ ab,
                                                        const unsigned short* __restrict__ wT,
                                                        float* __restrict__ out) {
  __shared__ unsigned short lA[2 * 128 * 32];
  __shared__ unsigned short lB[2 * 128 * 32];
  f32x4 acc[4][4];
  const int nbx = C_ / 128;
  int flat = xcd_swz(blockIdx.y * nbx + blockIdx.x, nbx * ((B_ * T_) / 128));
  const int m0 = (flat / nbx) * 128, n0 = (flat % nbx) * 128;
  gemm_core2(ab, wT, C_, m0, n0, lA, lB, acc);
  const int t = threadIdx.x, lane = t & 63, w = t >> 6;
  const int wm = w >> 1, wn = w & 1, g = lane >> 4, r16 = lane & 15;
  #pragma unroll
  for (int mi = 0; mi < 4; ++mi)
    #pragma unroll
    for (int ni = 0; ni < 4; ++ni)
      #pragma unroll
      for (int j = 0; j < 4; ++j) {
        int gm = m0 + wm * 64 + mi * 16 + g * 4 + j;
        int gn = n0 + wn * 64 + ni * 16 + r16;
        out[(size_t)gm * C_ + gn] = acc[mi][ni][j];
      }
}

// ---------------- Flash attention v13 (unchanged, verified round 13) ----------------
__global__ __launch_bounds__(256, 4) void attn_kernel(const unsigned short* __restrict__ qb,
                                                      const unsigned short* __restrict__ kb,
                                                      const unsigned short* __restrict__ vb,
                                                      unsigned short* __restrict__ ao,
                                                      unsigned short* __restrict__ partB,
                                                      float* __restrict__ mlbuf) {
  __shared__ unsigned short LDS[20480];
  const int L = blockIdx.x;
  const int inner = L >> 3;
  const int bh = (L & 7) * 4 + (inner / 48);
  const int bx = inner % 48;
  int tile, kvLo, kvHi, mode;   // mode: 0=full, 1=halfA, 2=halfB
  if (bx < 16)      { tile = 16 + bx; kvLo = 0;  kvHi = 16;       mode = 1; }
  else if (bx < 32) { tile = 47 - bx; kvLo = 16; kvHi = tile + 1; mode = 2; }
  else              { tile = 47 - bx; kvLo = 0;  kvHi = tile + 1; mode = 0; }
  const int qt0 = tile * 64;
  const int len = kvHi - kvLo;
  const int t = threadIdx.x, lane = t & 63, w4 = t >> 6;   // w4 in 0..3
  const int g = lane >> 4, r16 = lane & 15;

  const unsigned short* Q  = qb + (size_t)bh * (T_ * HD_);
  const unsigned short* Kp = kb + (size_t)bh * (T_ * HD_);
  const unsigned short* Vp = vb + (size_t)bh * (T_ * HD_);

  // Q fragments (B-operand: lane holds Q[q=r16][k-octet g]), pre-scaled 1/8
  bf16x8 qf[2];
  {
    int qrow = qt0 + w4 * 16 + r16;
    #pragma unroll
    for (int kk = 0; kk < 2; ++kk) {
      us8v raw = *(const us8v*)(Q + (size_t)qrow * HD_ + kk * 32 + g * 8);
      bf16x8 qv;
      #pragma unroll
      for (int j = 0; j < 8; ++j) qv[j] = (__bf16)(bf2f(raw[j]) * 0.125f);
      qf[kk] = qv;
    }
  }

  f32x4 o[4];
  #pragma unroll
  for (int c = 0; c < 4; ++c) o[c] = (f32x4){0.f, 0.f, 0.f, 0.f};
  float mrun = -__builtin_inff(), lrun = 0.f;

  // staging constants (verified formulas)
  const int kr0 = t >> 3,         kp0 = (t & 7) ^ (kr0 & 7);   // rows 0..31
  const int kr1 = (t + 256) >> 3, kp1 = (t & 7) ^ (kr1 & 7);   // rows 32..63
  const int colp = (lane & 32) | ((lane & 12) << 1) | ((lane >> 2) & 4) | (lane & 3);
  const int cslot = colp >> 3, cwithin = colp & 7;

  // prologue: batches 0 and 1 (K DMA then V regs; 4 VMEM ops per batch)
  gload16(Kp + (size_t)(kvLo * 64 + kr0) * HD_ + kp0 * 8, LDS + t * 8);
  gload16(Kp + (size_t)(kvLo * 64 + kr1) * HD_ + kp1 * 8, LDS + (t + 256) * 8);
  us8v nvA0 = *(const us8v*)(Vp + (size_t)(kvLo * 64 + lane) * HD_ + w4 * 16);
  us8v nvA1 = *(const us8v*)(Vp + (size_t)(kvLo * 64 + lane) * HD_ + w4 * 16 + 8);
  us8v nvB0, nvB1;
  if (len > 1) {
    const int k1 = (kvLo + 1) * 64;
    gload16(Kp + (size_t)(k1 + kr0) * HD_ + kp0 * 8, LDS + 4096 + t * 8);
    gload16(Kp + (size_t)(k1 + kr1) * HD_ + kp1 * 8, LDS + 4096 + (t + 256) * 8);
    nvB0 = *(const us8v*)(Vp + (size_t)(k1 + lane) * HD_ + w4 * 16);
    nvB1 = *(const us8v*)(Vp + (size_t)(k1 + lane) * HD_ + w4 * 16 + 8);
  }

  for (int ii = 0; ii < len; ++ii) {
    const int it = kvLo + ii;
    const unsigned short* Kl = LDS + (ii % 3) * 4096;
    unsigned short* Vt = LDS + 12288 + (ii & 1) * 4096;

    if (ii + 1 < len) { asm volatile("s_waitcnt vmcnt(4)" ::: "memory"); }
    else              { asm volatile("s_waitcnt vmcnt(0)" ::: "memory"); }
    {
      us8v v0, v1;
      if (ii & 1) { v0 = nvB0; v1 = nvB1; } else { v0 = nvA0; v1 = nvA1; }
      #pragma unroll
      for (int u = 0; u < 8; ++u) {
        int d = w4 * 16 + u;                             // d&7 == u
        Vt[d * 64 + ((cslot ^ u) << 3) + cwithin] = v0[u];
      }
      #pragma unroll
      for (int u = 0; u < 8; ++u) {
        int d = w4 * 16 + 8 + u;
        Vt[d * 64 + ((cslot ^ u) << 3) + cwithin] = v1[u];
      }
    }
    __syncthreads();

    if (ii + 2 < len) {    // issue batch ii+2 (buf (ii+2)%3, nv set ii&1 — just freed)
      const int kn = (it + 2) * 64;
      unsigned short* Kn = LDS + ((ii + 2) % 3) * 4096;
      gload16(Kp + (size_t)(kn + kr0) * HD_ + kp0 * 8, Kn + t * 8);
      gload16(Kp + (size_t)(kn + kr1) * HD_ + kp1 * 8, Kn + (t + 256) * 8);
      if (ii & 1) {
        nvB0 = *(const us8v*)(Vp + (size_t)(kn + lane) * HD_ + w4 * 16);
        nvB1 = *(const us8v*)(Vp + (size_t)(kn + lane) * HD_ + w4 * 16 + 8);
      } else {
        nvA0 = *(const us8v*)(Vp + (size_t)(kn + lane) * HD_ + w4 * 16);
        nvA1 = *(const us8v*)(Vp + (size_t)(kn + lane) * HD_ + w4 * 16 + 8);
      }
    }

    {
      // S^T = K @ Q^T : s4t[c][j] = S[q=r16-row][kv = it*64 + 16c + 4g + j]
      f32x4 s4t[4];
      #pragma unroll
      for (int c = 0; c < 4; ++c) s4t[c] = (f32x4){0.f, 0.f, 0.f, 0.f};
      __builtin_amdgcn_s_setprio(1);
      #pragma unroll
      for (int c = 0; c < 4; ++c)
        #pragma unroll
        for (int kk = 0; kk < 2; ++kk) {
          int r = c * 16 + r16;
          int ps = (kk * 4 + g) ^ (r & 7);
          bf16x8 kf = *(const bf16x8*)(Kl + r * 64 + ps * 8);
          s4t[c] = mfma16(kf, qf[kk], s4t[c]);
        }
      __builtin_amdgcn_s_setprio(0);
      if (it == tile) {   // diagonal tile: mask kv_local > q_local
        int qloc = w4 * 16 + r16;
        #pragma unroll
        for (int c = 0; c < 4; ++c)
          #pragma unroll
          for (int j = 0; j < 4; ++j)
            if (c * 16 + g * 4 + j > qloc) s4t[c][j] = -1e30f;
      }
      // row max via max3-triples
      float t0 = fmaxf(fmaxf(s4t[0][0], s4t[0][1]), s4t[0][2]);
      float t1 = fmaxf(fmaxf(s4t[0][3], s4t[1][0]), s4t[1][1]);
      float t2 = fmaxf(fmaxf(s4t[1][2], s4t[1][3]), s4t[2][0]);
      float t3 = fmaxf(fmaxf(s4t[2][1], s4t[2][2]), s4t[2][3]);
      float t4 = fmaxf(fmaxf(s4t[3][0], s4t[3][1]), s4t[3][2]);
      float mx = fmaxf(fmaxf(fmaxf(t0, t1), fmaxf(t2, t3)),
                       fmaxf(t4, s4t[3][3]));
      mx = fmaxf(mx, __shfl_xor(mx, 16));
      mx = fmaxf(mx, __shfl_xor(mx, 32));
      // T13 defer-max: only rescale when max grew by > 8
      if (!__all(mx - mrun <= 8.0f)) {
        float mn = fmaxf(mrun, mx);
        float alpha = __expf(mrun - mn);
        mrun = mn;
        lrun *= alpha;
        #pragma unroll
        for (int c = 0; c < 4; ++c)
          #pragma unroll
          for (int j = 0; j < 4; ++j) o[c][j] *= alpha;
      }
      // P = exp(S - mrun); tree-sum
      float ps4[4];
      #pragma unroll
      for (int c = 0; c < 4; ++c) {
        #pragma unroll
        for (int j = 0; j < 4; ++j) s4t[c][j] = __expf(s4t[c][j] - mrun);
        ps4[c] = (s4t[c][0] + s4t[c][1]) + (s4t[c][2] + s4t[c][3]);
      }
      float rs = (ps4[0] + ps4[1]) + (ps4[2] + ps4[3]);
      rs += __shfl_xor(rs, 16);
      rs += __shfl_xor(rs, 32);
      lrun += rs;

      // P^T fragments in-register (B-operand): p[4h+e] = s4t[2kk+h][e]
      bf16x8 pf[2];
      #pragma unroll
      for (int kk = 0; kk < 2; ++kk) {
        bf16x8 p;
        #pragma unroll
        for (int j = 0; j < 4; ++j) {
          p[j]     = (__bf16)s4t[2 * kk][j];
          p[4 + j] = (__bf16)s4t[2 * kk + 1][j];
        }
        pf[kk] = p;
      }
      // O^T += V^T @ P^T : A-fragment = swizzled b128 from Vt
      __builtin_amdgcn_s_setprio(1);
      #pragma unroll
      for (int c = 0; c < 4; ++c) {
        int rv = c * 16 + r16;
        #pragma unroll
        for (int kk = 0; kk < 2; ++kk) {
          int slot = (4 * kk + g) ^ (r16 & 7);
          bf16x8 vf = *(const bf16x8*)(Vt + rv * 64 + slot * 8);
          o[c] = mfma16(vf, pf[kk], o[c]);
        }
      }
      __builtin_amdgcn_s_setprio(0);
    }
  }

  // write (m,l) for split halves (rows lane-owned by g==0 lanes)
  if (mode && g == 0) {
    int prow = (bh * 16 + (tile - 16)) * 64 + w4 * 16 + r16;
    float* mlp = mlbuf + (size_t)prow * 4;
    if (mode == 1) { mlp[0] = mrun; mlp[1] = lrun; }
    else           { mlp[2] = mrun; mlp[3] = lrun; }
  }

  // epilogue: normalized O -> unused K buffer (len%3) transpose -> coalesced store
  unsigned short* ep = LDS + (len % 3) * 4096 + w4 * 1024;
  float inv = 1.f / lrun;
  #pragma unroll
  for (int c = 0; c < 4; ++c) {
    us4v pk;
    #pragma unroll
    for (int j = 0; j < 4; ++j) pk[j] = f2bf(o[c][j] * inv);
    int slot = (4 * c + g) ^ r16;
    *(us4v*)(ep + r16 * 64 + slot * 4) = pk;
  }
  asm volatile("s_waitcnt lgkmcnt(0)" ::: "memory");
  __builtin_amdgcn_sched_barrier(0);
  {
    int q = lane >> 2, seg = lane & 3;
    us4v a0 = *(const us4v*)(ep + q * 64 + (((seg * 4 + 0) ^ q) & 15) * 4);
    us4v a1 = *(const us4v*)(ep + q * 64 + (((seg * 4 + 1) ^ q) & 15) * 4);
    us4v a2 = *(const us4v*)(ep + q * 64 + (((seg * 4 + 2) ^ q) & 15) * 4);
    us4v a3 = *(const us4v*)(ep + q * 64 + (((seg * 4 + 3) ^ q) & 15) * 4);
    us8v o0 = {a0[0],a0[1],a0[2],a0[3],a1[0],a1[1],a1[2],a1[3]};
    us8v o1 = {a2[0],a2[1],a2[2],a2[3],a3[0],a3[1],a3[2],a3[3]};
    if (mode != 2) {
      size_t rowg = (size_t)(bh >> 4) * T_ + qt0 + w4 * 16 + q;
      int colg = (bh & 15) * 64 + seg * 16;
      *(us8v*)(ao + rowg * C_ + colg)     = o0;
      *(us8v*)(ao + rowg * C_ + colg + 8) = o1;
    } else {
      size_t prow = (size_t)(bh * 16 + (tile - 16)) * 64 + w4 * 16 + q;
      *(us8v*)(partB + prow * 64 + seg * 16)     = o0;
      *(us8v*)(partB + prow * 64 + seg * 16 + 8) = o1;
    }
  }
}

// ---------------- merge kernel: combine halfA (in ao) with halfB ----------------
__global__ __launch_bounds__(256) void attn_merge_kernel(unsigned short* __restrict__ ao,
                                                         const unsigned short* __restrict__ partB,
                                                         const float* __restrict__ mlbuf) {
  const int blk = blockIdx.x;          // 512 = 32 bh x 16 ti
  const int bh = blk >> 4, ti = blk & 15;
  const int t = threadIdx.x;
  const int row = t >> 2, seg = t & 3;
  const size_t prow = (size_t)(bh * 16 + ti) * 64 + row;
  const float* mlp = mlbuf + prow * 4;
  float mA = mlp[0], lA = mlp[1], mB = mlp[2], lB = mlp[3];
  float m = fmaxf(mA, mB);
  float wA = lA * __expf(mA - m), wB = lB * __expf(mB - m);
  float rinv = 1.f / (wA + wB);
  wA *= rinv; wB *= rinv;
  size_t rowg = (size_t)(bh >> 4) * T_ + (16 + ti) * 64 + row;
  unsigned short* aop = ao + rowg * C_ + (bh & 15) * 64 + seg * 16;
  const unsigned short* obp = partB + prow * 64 + seg * 16;
  us8v oa0 = *(const us8v*)(aop);
  us8v oa1 = *(const us8v*)(aop + 8);
  us8v ob0 = *(const us8v*)(obp);
  us8v ob1 = *(const us8v*)(obp + 8);
  us8v r0, r1;
  #pragma unroll
  for (int j = 0; j < 8; ++j) {
    r0[j] = f2bf(bf2f(oa0[j]) * wA + bf2f(ob0[j]) * wB);
    r1[j] = f2bf(bf2f(oa1[j]) * wA + bf2f(ob1[j]) * wB);
  }
  *(us8v*)(aop)     = r0;
  *(us8v*)(aop + 8) = r1;
}

// ---------------- launch ----------------
extern "C" void kernel_launch(void* const* d_in, const int* in_sizes, int n_in,
                              void* d_out, int out_size, void* d_ws, size_t ws_size,
                              hipStream_t stream) {
  const float* x      = (const float*)d_in[0];
  const float* w_qkv  = (const float*)d_in[1];
  const float* w_proj = (const float*)d_in[2];
  float* out = (float*)d_out;
  char* ws = (char*)d_ws;

  unsigned short* xb     = (unsigned short*)(ws);              // 8 MB (reused as ao)
  unsigned short* wqkvT  = (unsigned short*)(ws + 8388608);    // 6 MB (reused: partB+ml)
  unsigned short* wprojT = (unsigned short*)(ws + 14680064);   // 2 MB
  unsigned short* qb     = (unsigned short*)(ws + 16777216);   // 8 MB
  unsigned short* kb     = (unsigned short*)(ws + 25165824);   // 8 MB
  unsigned short* vb     = (unsigned short*)(ws + 33554432);   // 8 MB
  unsigned short* ao     = xb;
  // partials live in the wqkvT region (dead after gemm_qkv):
  unsigned short* partB  = wqkvT;                              // 4 MB (32*16*64 rows x 64 d)
  float*          mlbuf  = (float*)(ws + 8388608 + 4194304);   // 512 KB (rows x 4 f32)

  cast_x_kernel<<<4096, 256, 0, stream>>>((const float4*)x, (us4v*)xb);
  transpose_cast_kernel<<<dim3(3 * C_ / 32, C_ / 32), dim3(32, 8), 0, stream>>>(
      w_qkv, wqkvT, C_, 3 * C_);
  transpose_cast_kernel<<<dim3(C_ / 32, C_ / 32), dim3(32, 8), 0, stream>>>(
      w_proj, wprojT, C_, C_);
  gemm_qkv_kernel<<<dim3(3 * C_ / 128, (B_ * T_) / 128), 256, 0, stream>>>(
      xb, wqkvT, qb, kb, vb);
  attn_kernel<<<dim3(1536), 256, 0, stream>>>(qb, kb, vb, ao, partB, mlbuf);
  attn_merge_kernel<<<512, 256, 0, stream>>>(ao, partB, mlbuf);
  gemm_proj_kernel<<<dim3(C_ / 128, (B_ * T_) / 128), 256, 0, stream>>>(
      ao, wprojT, out);
}

// Round 16
// 120.683 us; speedup vs baseline: 1.1438x; 1.1296x over previous
//
#include <hip/hip_runtime.h>
#include <hip/hip_bf16.h>
#include <stdint.h>

typedef __bf16 bf16x8 __attribute__((ext_vector_type(8)));
typedef float f32x4 __attribute__((ext_vector_type(4)));
typedef unsigned short us4v __attribute__((ext_vector_type(4)));
typedef unsigned short us8v __attribute__((ext_vector_type(8)));

#define B_   2
#define T_   2048
#define C_   1024
#define NH_  16
#define HD_  64

__device__ __forceinline__ unsigned short f2bf(float f) {
  unsigned int u = __builtin_bit_cast(unsigned int, f);
  u += 0x7fffu + ((u >> 16) & 1u);           // RNE
  return (unsigned short)(u >> 16);
}
__device__ __forceinline__ float bf2f(unsigned short u) {
  unsigned int x = ((unsigned int)u) << 16;
  return __builtin_bit_cast(float, x);
}

__device__ __forceinline__ void gload16(const void* g, void* l) {
  __builtin_amdgcn_global_load_lds(
      (const __attribute__((address_space(1))) unsigned int*)g,
      (__attribute__((address_space(3))) unsigned int*)l, 16, 0, 0);
}

__device__ __forceinline__ f32x4 mfma16(bf16x8 a, bf16x8 b, f32x4 c) {
  return __builtin_amdgcn_mfma_f32_16x16x32_bf16(a, b, c, 0, 0, 0);
}

// ---------------- fused prep: cast_x + both weight transposes, ONE dispatch ----------------
// blocks [0,4096): cast x -> bf16.  [4096,7168): transpose w_qkv (96x32 tiles).
// [7168,8192): transpose w_proj (32x32 tiles). Whole-block branching, no
// divergent barriers. Per-branch code identical to the verified kernels.
__global__ __launch_bounds__(256) void prep_kernel(const float* __restrict__ x,
                                                   unsigned short* __restrict__ xb,
                                                   const float* __restrict__ w_qkv,
                                                   unsigned short* __restrict__ wqkvT,
                                                   const float* __restrict__ w_proj,
                                                   unsigned short* __restrict__ wprojT) {
  __shared__ float tile[32][33];
  const int b = blockIdx.x, t = threadIdx.x;
  if (b < 4096) {
    int i = b * 256 + t;
    float4 f = ((const float4*)x)[i];
    us4v o; o[0] = f2bf(f.x); o[1] = f2bf(f.y); o[2] = f2bf(f.z); o[3] = f2bf(f.w);
    ((us4v*)xb)[i] = o;
    return;
  }
  const float* w; unsigned short* wT; int N, tb;
  if (b < 7168) { tb = b - 4096; w = w_qkv;  wT = wqkvT;  N = 3 * C_; }
  else          { tb = b - 7168; w = w_proj; wT = wprojT; N = C_; }
  const int nx = N / 32;
  const int n0 = (tb % nx) * 32, k0 = (tb / nx) * 32;
  const int tx = t & 31, ty = t >> 5;   // 32 x 8
  #pragma unroll
  for (int i = 0; i < 4; ++i)
    tile[ty + 8*i][tx] = w[(size_t)(k0 + ty + 8*i) * N + n0 + tx];
  __syncthreads();
  #pragma unroll
  for (int i = 0; i < 4; ++i)
    wT[(size_t)(n0 + ty + 8*i) * C_ + k0 + tx] = f2bf(tile[tx][ty + 8*i]);
}

// ---------------- GEMM core (verified round 0 — structural ceiling ~870 TF) ----------------
__device__ __forceinline__ void gemm_core(const unsigned short* __restrict__ A,
                                          const unsigned short* __restrict__ Bt,
                                          int K, int m0, int n0,
                                          unsigned short* lA, unsigned short* lB,
                                          f32x4 acc[4][4]) {
  const int t = threadIdx.x;
  const int lane = t & 63, w = t >> 6;
  const int wm = w >> 1, wn = w & 1;
  const int g = lane >> 4, r16 = lane & 15;
  #pragma unroll
  for (int i = 0; i < 4; ++i)
    #pragma unroll
    for (int j = 0; j < 4; ++j) acc[i][j] = (f32x4){0.f, 0.f, 0.f, 0.f};

  for (int k0 = 0; k0 < K; k0 += 64) {
    #pragma unroll
    for (int i = 0; i < 4; ++i) {
      int slot = i * 256 + t;
      int r = slot >> 3, p = slot & 7;
      int q = p ^ (r & 7);
      gload16(A  + (size_t)(m0 + r) * K + k0 + q * 8, lA + slot * 8);
      gload16(Bt + (size_t)(n0 + r) * K + k0 + q * 8, lB + slot * 8);
    }
    asm volatile("s_waitcnt vmcnt(0)" ::: "memory");
    __syncthreads();

    bf16x8 af[4][2], bfr[4][2];
    #pragma unroll
    for (int mi = 0; mi < 4; ++mi)
      #pragma unroll
      for (int kk = 0; kk < 2; ++kk) {
        int r = wm * 64 + mi * 16 + r16;
        int ps = (kk * 4 + g) ^ (r & 7);
        af[mi][kk] = *(const bf16x8*)(lA + r * 64 + ps * 8);
      }
    #pragma unroll
    for (int ni = 0; ni < 4; ++ni)
      #pragma unroll
      for (int kk = 0; kk < 2; ++kk) {
        int r = wn * 64 + ni * 16 + r16;
        int ps = (kk * 4 + g) ^ (r & 7);
        bfr[ni][kk] = *(const bf16x8*)(lB + r * 64 + ps * 8);
      }
    #pragma unroll
    for (int mi = 0; mi < 4; ++mi)
      #pragma unroll
      for (int ni = 0; ni < 4; ++ni)
        #pragma unroll
        for (int kk = 0; kk < 2; ++kk)
          acc[mi][ni] = mfma16(af[mi][kk], bfr[ni][kk], acc[mi][ni]);
    __syncthreads();
  }
}

// XCD-aware bijective swizzle of the linear workgroup id (nwg % 8 == 0)
__device__ __forceinline__ int xcd_swz(int flat, int nwg) {
  int cpx = nwg >> 3;
  return (flat & 7) * cpx + (flat >> 3);
}

__global__ __launch_bounds__(256) void gemm_qkv_kernel(const unsigned short* __restrict__ xb,
                                                       const unsigned short* __restrict__ wT,
                                                       unsigned short* __restrict__ qb,
                                                       unsigned short* __restrict__ kb,
                                                       unsigned short* __restrict__ vb) {
  __shared__ unsigned short lA[128 * 64];
  __shared__ unsigned short lB[128 * 64];
  f32x4 acc[4][4];
  const int nbx = 3 * C_ / 128;
  int flat = xcd_swz(blockIdx.y * nbx + blockIdx.x, nbx * ((B_ * T_) / 128));
  const int m0 = (flat / nbx) * 128, n0 = (flat % nbx) * 128;
  gemm_core(xb, wT, C_, m0, n0, lA, lB, acc);
  const int t = threadIdx.x, lane = t & 63, w = t >> 6;
  const int wm = w >> 1, wn = w & 1, g = lane >> 4, r16 = lane & 15;
  #pragma unroll
  for (int mi = 0; mi < 4; ++mi)
    #pragma unroll
    for (int ni = 0; ni < 4; ++ni)
      #pragma unroll
      for (int j = 0; j < 4; ++j) {
        int gm = m0 + wm * 64 + mi * 16 + g * 4 + j;
        int gn = n0 + wn * 64 + ni * 16 + r16;
        int b = gm >> 11, tt = gm & 2047;
        int s = gn >> 10, rem = gn & 1023;
        int h = rem >> 6, d = rem & 63;
        unsigned short val = f2bf(acc[mi][ni][j]);
        size_t idx = ((size_t)(b * NH_ + h) * T_ + tt) * HD_ + d;
        if (s == 0)      qb[idx] = val;
        else if (s == 1) kb[idx] = val;
        else             vb[idx] = val;
      }
}

__global__ __launch_bounds__(256) void gemm_proj_kernel(const unsigned short* __restrict__ ab,
                                                        const unsigned short* __restrict__ wT,
                                                        float* __restrict__ out) {
  __shared__ unsigned short lA[128 * 64];
  __shared__ unsigned short lB[128 * 64];
  f32x4 acc[4][4];
  const int nbx = C_ / 128;
  int flat = xcd_swz(blockIdx.y * nbx + blockIdx.x, nbx * ((B_ * T_) / 128));
  const int m0 = (flat / nbx) * 128, n0 = (flat % nbx) * 128;
  gemm_core(ab, wT, C_, m0, n0, lA, lB, acc);
  const int t = threadIdx.x, lane = t & 63, w = t >> 6;
  const int wm = w >> 1, wn = w & 1, g = lane >> 4, r16 = lane & 15;
  #pragma unroll
  for (int mi = 0; mi < 4; ++mi)
    #pragma unroll
    for (int ni = 0; ni < 4; ++ni)
      #pragma unroll
      for (int j = 0; j < 4; ++j) {
        int gm = m0 + wm * 64 + mi * 16 + g * 4 + j;
        int gn = n0 + wn * 64 + ni * 16 + r16;
        out[(size_t)gm * C_ + gn] = acc[mi][ni][j];
      }
}

// ---------------- Flash attention v13 (verified round 13) ----------------
__global__ __launch_bounds__(256, 4) void attn_kernel(const unsigned short* __restrict__ qb,
                                                      const unsigned short* __restrict__ kb,
                                                      const unsigned short* __restrict__ vb,
                                                      unsigned short* __restrict__ ao,
                                                      unsigned short* __restrict__ partB,
                                                      float* __restrict__ mlbuf) {
  __shared__ unsigned short LDS[20480];
  const int L = blockIdx.x;
  const int inner = L >> 3;
  const int bh = (L & 7) * 4 + (inner / 48);
  const int bx = inner % 48;
  int tile, kvLo, kvHi, mode;   // mode: 0=full, 1=halfA, 2=halfB
  if (bx < 16)      { tile = 16 + bx; kvLo = 0;  kvHi = 16;       mode = 1; }
  else if (bx < 32) { tile = 47 - bx; kvLo = 16; kvHi = tile + 1; mode = 2; }
  else              { tile = 47 - bx; kvLo = 0;  kvHi = tile + 1; mode = 0; }
  const int qt0 = tile * 64;
  const int len = kvHi - kvLo;
  const int t = threadIdx.x, lane = t & 63, w4 = t >> 6;   // w4 in 0..3
  const int g = lane >> 4, r16 = lane & 15;

  const unsigned short* Q  = qb + (size_t)bh * (T_ * HD_);
  const unsigned short* Kp = kb + (size_t)bh * (T_ * HD_);
  const unsigned short* Vp = vb + (size_t)bh * (T_ * HD_);

  // Q fragments (B-operand: lane holds Q[q=r16][k-octet g]), pre-scaled 1/8
  bf16x8 qf[2];
  {
    int qrow = qt0 + w4 * 16 + r16;
    #pragma unroll
    for (int kk = 0; kk < 2; ++kk) {
      us8v raw = *(const us8v*)(Q + (size_t)qrow * HD_ + kk * 32 + g * 8);
      bf16x8 qv;
      #pragma unroll
      for (int j = 0; j < 8; ++j) qv[j] = (__bf16)(bf2f(raw[j]) * 0.125f);
      qf[kk] = qv;
    }
  }

  f32x4 o[4];
  #pragma unroll
  for (int c = 0; c < 4; ++c) o[c] = (f32x4){0.f, 0.f, 0.f, 0.f};
  float mrun = -__builtin_inff(), lrun = 0.f;

  // staging constants (verified formulas)
  const int kr0 = t >> 3,         kp0 = (t & 7) ^ (kr0 & 7);   // rows 0..31
  const int kr1 = (t + 256) >> 3, kp1 = (t & 7) ^ (kr1 & 7);   // rows 32..63
  const int colp = (lane & 32) | ((lane & 12) << 1) | ((lane >> 2) & 4) | (lane & 3);
  const int cslot = colp >> 3, cwithin = colp & 7;

  // prologue: batches 0 and 1 (K DMA then V regs; 4 VMEM ops per batch)
  gload16(Kp + (size_t)(kvLo * 64 + kr0) * HD_ + kp0 * 8, LDS + t * 8);
  gload16(Kp + (size_t)(kvLo * 64 + kr1) * HD_ + kp1 * 8, LDS + (t + 256) * 8);
  us8v nvA0 = *(const us8v*)(Vp + (size_t)(kvLo * 64 + lane) * HD_ + w4 * 16);
  us8v nvA1 = *(const us8v*)(Vp + (size_t)(kvLo * 64 + lane) * HD_ + w4 * 16 + 8);
  us8v nvB0, nvB1;
  if (len > 1) {
    const int k1 = (kvLo + 1) * 64;
    gload16(Kp + (size_t)(k1 + kr0) * HD_ + kp0 * 8, LDS + 4096 + t * 8);
    gload16(Kp + (size_t)(k1 + kr1) * HD_ + kp1 * 8, LDS + 4096 + (t + 256) * 8);
    nvB0 = *(const us8v*)(Vp + (size_t)(k1 + lane) * HD_ + w4 * 16);
    nvB1 = *(const us8v*)(Vp + (size_t)(k1 + lane) * HD_ + w4 * 16 + 8);
  }

  for (int ii = 0; ii < len; ++ii) {
    const int it = kvLo + ii;
    const unsigned short* Kl = LDS + (ii % 3) * 4096;
    unsigned short* Vt = LDS + 12288 + (ii & 1) * 4096;

    if (ii + 1 < len) { asm volatile("s_waitcnt vmcnt(4)" ::: "memory"); }
    else              { asm volatile("s_waitcnt vmcnt(0)" ::: "memory"); }
    {
      us8v v0, v1;
      if (ii & 1) { v0 = nvB0; v1 = nvB1; } else { v0 = nvA0; v1 = nvA1; }
      #pragma unroll
      for (int u = 0; u < 8; ++u) {
        int d = w4 * 16 + u;                             // d&7 == u
        Vt[d * 64 + ((cslot ^ u) << 3) + cwithin] = v0[u];
      }
      #pragma unroll
      for (int u = 0; u < 8; ++u) {
        int d = w4 * 16 + 8 + u;
        Vt[d * 64 + ((cslot ^ u) << 3) + cwithin] = v1[u];
      }
    }
    __syncthreads();

    if (ii + 2 < len) {    // issue batch ii+2 (buf (ii+2)%3, nv set ii&1 — just freed)
      const int kn = (it + 2) * 64;
      unsigned short* Kn = LDS + ((ii + 2) % 3) * 4096;
      gload16(Kp + (size_t)(kn + kr0) * HD_ + kp0 * 8, Kn + t * 8);
      gload16(Kp + (size_t)(kn + kr1) * HD_ + kp1 * 8, Kn + (t + 256) * 8);
      if (ii & 1) {
        nvB0 = *(const us8v*)(Vp + (size_t)(kn + lane) * HD_ + w4 * 16);
        nvB1 = *(const us8v*)(Vp + (size_t)(kn + lane) * HD_ + w4 * 16 + 8);
      } else {
        nvA0 = *(const us8v*)(Vp + (size_t)(kn + lane) * HD_ + w4 * 16);
        nvA1 = *(const us8v*)(Vp + (size_t)(kn + lane) * HD_ + w4 * 16 + 8);
      }
    }

    {
      // S^T = K @ Q^T : s4t[c][j] = S[q=r16-row][kv = it*64 + 16c + 4g + j]
      f32x4 s4t[4];
      #pragma unroll
      for (int c = 0; c < 4; ++c) s4t[c] = (f32x4){0.f, 0.f, 0.f, 0.f};
      __builtin_amdgcn_s_setprio(1);
      #pragma unroll
      for (int c = 0; c < 4; ++c)
        #pragma unroll
        for (int kk = 0; kk < 2; ++kk) {
          int r = c * 16 + r16;
          int ps = (kk * 4 + g) ^ (r & 7);
          bf16x8 kf = *(const bf16x8*)(Kl + r * 64 + ps * 8);
          s4t[c] = mfma16(kf, qf[kk], s4t[c]);
        }
      __builtin_amdgcn_s_setprio(0);
      if (it == tile) {   // diagonal tile: mask kv_local > q_local
        int qloc = w4 * 16 + r16;
        #pragma unroll
        for (int c = 0; c < 4; ++c)
          #pragma unroll
          for (int j = 0; j < 4; ++j)
            if (c * 16 + g * 4 + j > qloc) s4t[c][j] = -1e30f;
      }
      // row max via max3-triples
      float t0 = fmaxf(fmaxf(s4t[0][0], s4t[0][1]), s4t[0][2]);
      float t1 = fmaxf(fmaxf(s4t[0][3], s4t[1][0]), s4t[1][1]);
      float t2 = fmaxf(fmaxf(s4t[1][2], s4t[1][3]), s4t[2][0]);
      float t3 = fmaxf(fmaxf(s4t[2][1], s4t[2][2]), s4t[2][3]);
      float t4 = fmaxf(fmaxf(s4t[3][0], s4t[3][1]), s4t[3][2]);
      float mx = fmaxf(fmaxf(fmaxf(t0, t1), fmaxf(t2, t3)),
                       fmaxf(t4, s4t[3][3]));
      mx = fmaxf(mx, __shfl_xor(mx, 16));
      mx = fmaxf(mx, __shfl_xor(mx, 32));
      // T13 defer-max: only rescale when max grew by > 8
      if (!__all(mx - mrun <= 8.0f)) {
        float mn = fmaxf(mrun, mx);
        float alpha = __expf(mrun - mn);
        mrun = mn;
        lrun *= alpha;
        #pragma unroll
        for (int c = 0; c < 4; ++c)
          #pragma unroll
          for (int j = 0; j < 4; ++j) o[c][j] *= alpha;
      }
      // P = exp(S - mrun); tree-sum
      float ps4[4];
      #pragma unroll
      for (int c = 0; c < 4; ++c) {
        #pragma unroll
        for (int j = 0; j < 4; ++j) s4t[c][j] = __expf(s4t[c][j] - mrun);
        ps4[c] = (s4t[c][0] + s4t[c][1]) + (s4t[c][2] + s4t[c][3]);
      }
      float rs = (ps4[0] + ps4[1]) + (ps4[2] + ps4[3]);
      rs += __shfl_xor(rs, 16);
      rs += __shfl_xor(rs, 32);
      lrun += rs;

      // P^T fragments in-register (B-operand): p[4h+e] = s4t[2kk+h][e]
      bf16x8 pf[2];
      #pragma unroll
      for (int kk = 0; kk < 2; ++kk) {
        bf16x8 p;
        #pragma unroll
        for (int j = 0; j < 4; ++j) {
          p[j]     = (__bf16)s4t[2 * kk][j];
          p[4 + j] = (__bf16)s4t[2 * kk + 1][j];
        }
        pf[kk] = p;
      }
      // O^T += V^T @ P^T : A-fragment = swizzled b128 from Vt
      __builtin_amdgcn_s_setprio(1);
      #pragma unroll
      for (int c = 0; c < 4; ++c) {
        int rv = c * 16 + r16;
        #pragma unroll
        for (int kk = 0; kk < 2; ++kk) {
          int slot = (4 * kk + g) ^ (r16 & 7);
          bf16x8 vf = *(const bf16x8*)(Vt + rv * 64 + slot * 8);
          o[c] = mfma16(vf, pf[kk], o[c]);
        }
      }
      __builtin_amdgcn_s_setprio(0);
    }
  }

  // write (m,l) for split halves (rows lane-owned by g==0 lanes)
  if (mode && g == 0) {
    int prow = (bh * 16 + (tile - 16)) * 64 + w4 * 16 + r16;
    float* mlp = mlbuf + (size_t)prow * 4;
    if (mode == 1) { mlp[0] = mrun; mlp[1] = lrun; }
    else           { mlp[2] = mrun; mlp[3] = lrun; }
  }

  // epilogue: normalized O -> unused K buffer (len%3) transpose -> coalesced store
  unsigned short* ep = LDS + (len % 3) * 4096 + w4 * 1024;
  float inv = 1.f / lrun;
  #pragma unroll
  for (int c = 0; c < 4; ++c) {
    us4v pk;
    #pragma unroll
    for (int j = 0; j < 4; ++j) pk[j] = f2bf(o[c][j] * inv);
    int slot = (4 * c + g) ^ r16;
    *(us4v*)(ep + r16 * 64 + slot * 4) = pk;
  }
  asm volatile("s_waitcnt lgkmcnt(0)" ::: "memory");
  __builtin_amdgcn_sched_barrier(0);
  {
    int q = lane >> 2, seg = lane & 3;
    us4v a0 = *(const us4v*)(ep + q * 64 + (((seg * 4 + 0) ^ q) & 15) * 4);
    us4v a1 = *(const us4v*)(ep + q * 64 + (((seg * 4 + 1) ^ q) & 15) * 4);
    us4v a2 = *(const us4v*)(ep + q * 64 + (((seg * 4 + 2) ^ q) & 15) * 4);
    us4v a3 = *(const us4v*)(ep + q * 64 + (((seg * 4 + 3) ^ q) & 15) * 4);
    us8v o0 = {a0[0],a0[1],a0[2],a0[3],a1[0],a1[1],a1[2],a1[3]};
    us8v o1 = {a2[0],a2[1],a2[2],a2[3],a3[0],a3[1],a3[2],a3[3]};
    if (mode != 2) {
      size_t rowg = (size_t)(bh >> 4) * T_ + qt0 + w4 * 16 + q;
      int colg = (bh & 15) * 64 + seg * 16;
      *(us8v*)(ao + rowg * C_ + colg)     = o0;
      *(us8v*)(ao + rowg * C_ + colg + 8) = o1;
    } else {
      size_t prow = (size_t)(bh * 16 + (tile - 16)) * 64 + w4 * 16 + q;
      *(us8v*)(partB + prow * 64 + seg * 16)     = o0;
      *(us8v*)(partB + prow * 64 + seg * 16 + 8) = o1;
    }
  }
}

// ---------------- merge kernel: combine halfA (in ao) with halfB ----------------
__global__ __launch_bounds__(256) void attn_merge_kernel(unsigned short* __restrict__ ao,
                                                         const unsigned short* __restrict__ partB,
                                                         const float* __restrict__ mlbuf) {
  const int blk = blockIdx.x;          // 512 = 32 bh x 16 ti
  const int bh = blk >> 4, ti = blk & 15;
  const int t = threadIdx.x;
  const int row = t >> 2, seg = t & 3;
  const size_t prow = (size_t)(bh * 16 + ti) * 64 + row;
  const float* mlp = mlbuf + prow * 4;
  float mA = mlp[0], lA = mlp[1], mB = mlp[2], lB = mlp[3];
  float m = fmaxf(mA, mB);
  float wA = lA * __expf(mA - m), wB = lB * __expf(mB - m);
  float rinv = 1.f / (wA + wB);
  wA *= rinv; wB *= rinv;
  size_t rowg = (size_t)(bh >> 4) * T_ + (16 + ti) * 64 + row;
  unsigned short* aop = ao + rowg * C_ + (bh & 15) * 64 + seg * 16;
  const unsigned short* obp = partB + prow * 64 + seg * 16;
  us8v oa0 = *(const us8v*)(aop);
  us8v oa1 = *(const us8v*)(aop + 8);
  us8v ob0 = *(const us8v*)(obp);
  us8v ob1 = *(const us8v*)(obp + 8);
  us8v r0, r1;
  #pragma unroll
  for (int j = 0; j < 8; ++j) {
    r0[j] = f2bf(bf2f(oa0[j]) * wA + bf2f(ob0[j]) * wB);
    r1[j] = f2bf(bf2f(oa1[j]) * wA + bf2f(ob1[j]) * wB);
  }
  *(us8v*)(aop)     = r0;
  *(us8v*)(aop + 8) = r1;
}

// ---------------- launch ----------------
extern "C" void kernel_launch(void* const* d_in, const int* in_sizes, int n_in,
                              void* d_out, int out_size, void* d_ws, size_t ws_size,
                              hipStream_t stream) {
  const float* x      = (const float*)d_in[0];
  const float* w_qkv  = (const float*)d_in[1];
  const float* w_proj = (const float*)d_in[2];
  float* out = (float*)d_out;
  char* ws = (char*)d_ws;

  unsigned short* xb     = (unsigned short*)(ws);              // 8 MB (reused as ao)
  unsigned short* wqkvT  = (unsigned short*)(ws + 8388608);    // 6 MB (reused: partB+ml)
  unsigned short* wprojT = (unsigned short*)(ws + 14680064);   // 2 MB
  unsigned short* qb     = (unsigned short*)(ws + 16777216);   // 8 MB
  unsigned short* kb     = (unsigned short*)(ws + 25165824);   // 8 MB
  unsigned short* vb     = (unsigned short*)(ws + 33554432);   // 8 MB
  unsigned short* ao     = xb;
  // partials live in the wqkvT region (dead after gemm_qkv):
  unsigned short* partB  = wqkvT;                              // 4 MB (32*16*64 rows x 64 d)
  float*          mlbuf  = (float*)(ws + 8388608 + 4194304);   // 512 KB (rows x 4 f32)

  prep_kernel<<<8192, 256, 0, stream>>>(x, xb, w_qkv, wqkvT, w_proj, wprojT);
  gemm_qkv_kernel<<<dim3(3 * C_ / 128, (B_ * T_) / 128), 256, 0, stream>>>(
      xb, wqkvT, qb, kb, vb);
  attn_kernel<<<dim3(1536), 256, 0, stream>>>(qb, kb, vb, ao, partB, mlbuf);
  attn_merge_kernel<<<512, 256, 0, stream>>>(ao, partB, mlbuf);
  gemm_proj_kernel<<<dim3(C_ / 128, (B_ * T_) / 128), 256, 0, stream>>>(
      ao, wprojT, out);
}